// Round 1
// baseline (1128.701 us; speedup 1.0000x reference)
//
#include <hip/hip_runtime.h>
#include <math.h>

// Problem constants (B=2, T=2048, D_MODEL=1024, H=16, D_K=64)
#define D_MODEL 1024
#define NHEADS  16
#define DK      64
#define TT      2048
#define BB      2
#define MM      (BB * TT)   // 4096 rows

// ---------------------------------------------------------------------------
// Kernel 1: fused QKV projection + RoPE epilogue.
//   C[m][o] = sum_c A[m][c] * W[o][c]     (A: [4096,1024], W: [1024,1024])
//   z = 0: Q (rope), 1: K (rope), 2: V (no rope)
//   output layout: dst[((b*H + h)*T + t)*DK + d]
// 64x64 tile, BK=16, 256 threads, 4x4 micro-tile per thread.
// ---------------------------------------------------------------------------
__global__ __launch_bounds__(256) void qkv_rope_kernel(
    const float* __restrict__ qin, const float* __restrict__ kin, const float* __restrict__ vin,
    const float* __restrict__ Wq,  const float* __restrict__ Wk,  const float* __restrict__ Wv,
    float* __restrict__ Qw, float* __restrict__ Kw, float* __restrict__ Vw)
{
    const int z = blockIdx.z;
    const float* __restrict__ A = (z == 0) ? qin : (z == 1) ? kin : vin;
    const float* __restrict__ W = (z == 0) ? Wq  : (z == 1) ? Wk  : Wv;
    float* __restrict__ dst     = (z == 0) ? Qw  : (z == 1) ? Kw  : Vw;

    // +4 pad keeps float4 rows 16B-aligned and transpose-writes at <=2-way conflict
    __shared__ float As[16][64 + 4];   // [k][m]
    __shared__ float Bs[16][64 + 4];   // [k][n]

    const int tid = threadIdx.x;
    const int tx = tid & 15, ty = tid >> 4;
    const int row0 = blockIdx.y << 6;
    const int col0 = blockIdx.x << 6;   // head h = blockIdx.x
    const int lr = tid >> 2;            // 0..63
    const int lc = (tid & 3) << 2;      // 0,4,8,12

    float acc[4][4] = {};

    for (int k0 = 0; k0 < D_MODEL; k0 += 16) {
        float4 av = *(const float4*)&A[(size_t)(row0 + lr) * D_MODEL + k0 + lc];
        float4 bv = *(const float4*)&W[(size_t)(col0 + lr) * D_MODEL + k0 + lc];
        As[lc + 0][lr] = av.x; As[lc + 1][lr] = av.y; As[lc + 2][lr] = av.z; As[lc + 3][lr] = av.w;
        Bs[lc + 0][lr] = bv.x; Bs[lc + 1][lr] = bv.y; Bs[lc + 2][lr] = bv.z; Bs[lc + 3][lr] = bv.w;
        __syncthreads();
#pragma unroll
        for (int kk = 0; kk < 16; ++kk) {
            float4 a = *(const float4*)&As[kk][ty << 2];
            float4 b = *(const float4*)&Bs[kk][tx << 2];
            const float aa[4] = {a.x, a.y, a.z, a.w};
            const float bb[4] = {b.x, b.y, b.z, b.w};
#pragma unroll
            for (int i = 0; i < 4; ++i)
#pragma unroll
                for (int j = 0; j < 4; ++j)
                    acc[i][j] = fmaf(aa[i], bb[j], acc[i][j]);
        }
        __syncthreads();
    }

    // Epilogue: optional RoPE, write to [B,H,T,DK] layout.
    const int h  = blockIdx.x;          // one head per column tile (64 cols)
    const int d0 = tx << 2;             // 0..60, within head; pairs (d0,d0+1),(d0+2,d0+3)
    const bool rope = (z < 2);

    float inv0 = 0.f, inv1 = 0.f;
    if (rope) {
        const float lb_over_dk = 9.210340371976184f / 64.0f;  // ln(10000)/64
        inv0 = __expf(-(float)(d0)     * lb_over_dk);
        inv1 = __expf(-(float)(d0 + 2) * lb_over_dk);
    }

#pragma unroll
    for (int i = 0; i < 4; ++i) {
        const int m = row0 + (ty << 2) + i;
        const int t = m & (TT - 1);
        const int b = m >> 11;
        float4 o;
        if (rope) {
            float c0, s0, c1, s1;
            __sincosf((float)t * inv0, &s0, &c0);
            __sincosf((float)t * inv1, &s1, &c1);
            o.x = acc[i][0] * c0 - acc[i][1] * s0;
            o.y = acc[i][0] * s0 + acc[i][1] * c0;
            o.z = acc[i][2] * c1 - acc[i][3] * s1;
            o.w = acc[i][2] * s1 + acc[i][3] * c1;
        } else {
            o = make_float4(acc[i][0], acc[i][1], acc[i][2], acc[i][3]);
        }
        *(float4*)&dst[(((size_t)b * NHEADS + h) * TT + t) * DK + d0] = o;
    }
}

// ---------------------------------------------------------------------------
// Kernel 2: flash attention (fp32). One block = 64 Q rows of one (b,h).
// LDS: Qs [d][q] (transposed), KP union of K-transposed [d][k] and P [q][k],
// Vs [k][d]. Online softmax in registers (shfl_xor across the 16 tx lanes).
// ---------------------------------------------------------------------------
__global__ __launch_bounds__(256) void attn_kernel(
    const float* __restrict__ Qw, const float* __restrict__ Kw,
    const float* __restrict__ Vw, float* __restrict__ ctx)
{
    __shared__ float Qs[64][68];   // [d][q]
    __shared__ float KP[64][68];   // K as [d][k]; reused as P [q][k]
    __shared__ float Vs[64][68];   // [k][d]

    const int tid = threadIdx.x;
    const int tx = tid & 15, ty = tid >> 4;
    const int bh = blockIdx.y;                 // 0..31
    const int q0 = blockIdx.x << 6;
    const float* __restrict__ Qp = Qw + (size_t)bh * TT * DK;
    const float* __restrict__ Kp = Kw + (size_t)bh * TT * DK;
    const float* __restrict__ Vp = Vw + (size_t)bh * TT * DK;

    // Stage Q tile transposed: Qs[d][q]
#pragma unroll
    for (int it = 0; it < 4; ++it) {
        const int f4  = it * 256 + tid;        // 0..1023 float4 index
        const int row = f4 >> 4;               // 0..63
        const int c4  = (f4 & 15) << 2;        // 0..60
        float4 v = *(const float4*)&Qp[(size_t)(q0 + row) * DK + c4];
        Qs[c4 + 0][row] = v.x; Qs[c4 + 1][row] = v.y;
        Qs[c4 + 2][row] = v.z; Qs[c4 + 3][row] = v.w;
    }

    float m_i[4], l_i[4], acc[4][4] = {};
#pragma unroll
    for (int i = 0; i < 4; ++i) { m_i[i] = -INFINITY; l_i[i] = 0.0f; }

    for (int kt = 0; kt < TT; kt += 64) {
        // Stage K (transposed) and V (straight, padded rows)
#pragma unroll
        for (int it = 0; it < 4; ++it) {
            const int f4  = it * 256 + tid;
            const int row = f4 >> 4;
            const int c4  = (f4 & 15) << 2;
            float4 kv = *(const float4*)&Kp[(size_t)(kt + row) * DK + c4];
            KP[c4 + 0][row] = kv.x; KP[c4 + 1][row] = kv.y;
            KP[c4 + 2][row] = kv.z; KP[c4 + 3][row] = kv.w;
            *(float4*)&Vs[row][c4] = *(const float4*)&Vp[(size_t)(kt + row) * DK + c4];
        }
        __syncthreads();   // (a) staging visible

        // S = Q K^T for this 64x64 tile; thread owns rows ty*4.., cols tx*4..
        float s[4][4] = {};
#pragma unroll
        for (int d = 0; d < 64; ++d) {
            float4 a = *(const float4*)&Qs[d][ty << 2];
            float4 b = *(const float4*)&KP[d][tx << 2];
            const float aa[4] = {a.x, a.y, a.z, a.w};
            const float bb[4] = {b.x, b.y, b.z, b.w};
#pragma unroll
            for (int i = 0; i < 4; ++i)
#pragma unroll
                for (int j = 0; j < 4; ++j)
                    s[i][j] = fmaf(aa[i], bb[j], s[i][j]);
        }

        // Online softmax (scale 1/sqrt(64) = 0.125)
#pragma unroll
        for (int i = 0; i < 4; ++i) {
#pragma unroll
            for (int j = 0; j < 4; ++j) s[i][j] *= 0.125f;
            float rm = fmaxf(fmaxf(s[i][0], s[i][1]), fmaxf(s[i][2], s[i][3]));
            rm = fmaxf(rm, __shfl_xor(rm, 1));
            rm = fmaxf(rm, __shfl_xor(rm, 2));
            rm = fmaxf(rm, __shfl_xor(rm, 4));
            rm = fmaxf(rm, __shfl_xor(rm, 8));
            const float mnew  = fmaxf(m_i[i], rm);
            const float alpha = expf(m_i[i] - mnew);
            m_i[i] = mnew;
            float rs = 0.0f;
#pragma unroll
            for (int j = 0; j < 4; ++j) { s[i][j] = expf(s[i][j] - mnew); rs += s[i][j]; }
            rs += __shfl_xor(rs, 1);
            rs += __shfl_xor(rs, 2);
            rs += __shfl_xor(rs, 4);
            rs += __shfl_xor(rs, 8);
            l_i[i] = l_i[i] * alpha + rs;
#pragma unroll
            for (int j = 0; j < 4; ++j) acc[i][j] *= alpha;
        }
        __syncthreads();   // (b) all K reads done; KP may be overwritten with P

        // Write P into KP as [q][k]
#pragma unroll
        for (int i = 0; i < 4; ++i)
            *(float4*)&KP[(ty << 2) + i][tx << 2] = make_float4(s[i][0], s[i][1], s[i][2], s[i][3]);
        __syncthreads();   // (c) P visible

        // O += P V : thread owns rows ty*4.., output cols tx*4..
#pragma unroll
        for (int c = 0; c < 16; ++c) {
            float vv[4][4];
#pragma unroll
            for (int j = 0; j < 4; ++j) {
                float4 t = *(const float4*)&Vs[(c << 2) + j][tx << 2];
                vv[j][0] = t.x; vv[j][1] = t.y; vv[j][2] = t.z; vv[j][3] = t.w;
            }
#pragma unroll
            for (int i = 0; i < 4; ++i) {
                float4 pr = *(const float4*)&KP[(ty << 2) + i][c << 2];
                const float pp[4] = {pr.x, pr.y, pr.z, pr.w};
#pragma unroll
                for (int j = 0; j < 4; ++j)
#pragma unroll
                    for (int dj = 0; dj < 4; ++dj)
                        acc[i][dj] = fmaf(pp[j], vv[j][dj], acc[i][dj]);
            }
        }
        __syncthreads();   // (d) PV reads done; safe to restage next tile
    }

    // Epilogue: normalize and write ctx[b*T + q][h*DK + d] (row-major [4096,1024])
    const int b = bh >> 4, h = bh & 15;
#pragma unroll
    for (int i = 0; i < 4; ++i) {
        const int qrow = q0 + (ty << 2) + i;
        const float inv = 1.0f / l_i[i];
        float4 o = make_float4(acc[i][0] * inv, acc[i][1] * inv, acc[i][2] * inv, acc[i][3] * inv);
        *(float4*)&ctx[((size_t)b * TT + qrow) * D_MODEL + h * DK + (tx << 2)] = o;
    }
}

// ---------------------------------------------------------------------------
// Kernel 3: output projection. out[m][o] = sum_c ctx[m][c] * W_o[o][c]
// Same tiled GEMM as kernel 1, plain row-major epilogue.
// ---------------------------------------------------------------------------
__global__ __launch_bounds__(256) void out_proj_kernel(
    const float* __restrict__ A, const float* __restrict__ W, float* __restrict__ C)
{
    __shared__ float As[16][64 + 4];
    __shared__ float Bs[16][64 + 4];

    const int tid = threadIdx.x;
    const int tx = tid & 15, ty = tid >> 4;
    const int row0 = blockIdx.y << 6;
    const int col0 = blockIdx.x << 6;
    const int lr = tid >> 2;
    const int lc = (tid & 3) << 2;

    float acc[4][4] = {};

    for (int k0 = 0; k0 < D_MODEL; k0 += 16) {
        float4 av = *(const float4*)&A[(size_t)(row0 + lr) * D_MODEL + k0 + lc];
        float4 bv = *(const float4*)&W[(size_t)(col0 + lr) * D_MODEL + k0 + lc];
        As[lc + 0][lr] = av.x; As[lc + 1][lr] = av.y; As[lc + 2][lr] = av.z; As[lc + 3][lr] = av.w;
        Bs[lc + 0][lr] = bv.x; Bs[lc + 1][lr] = bv.y; Bs[lc + 2][lr] = bv.z; Bs[lc + 3][lr] = bv.w;
        __syncthreads();
#pragma unroll
        for (int kk = 0; kk < 16; ++kk) {
            float4 a = *(const float4*)&As[kk][ty << 2];
            float4 b = *(const float4*)&Bs[kk][tx << 2];
            const float aa[4] = {a.x, a.y, a.z, a.w};
            const float bb[4] = {b.x, b.y, b.z, b.w};
#pragma unroll
            for (int i = 0; i < 4; ++i)
#pragma unroll
                for (int j = 0; j < 4; ++j)
                    acc[i][j] = fmaf(aa[i], bb[j], acc[i][j]);
        }
        __syncthreads();
    }

#pragma unroll
    for (int i = 0; i < 4; ++i) {
        const int m = row0 + (ty << 2) + i;
        *(float4*)&C[(size_t)m * D_MODEL + col0 + (tx << 2)] =
            make_float4(acc[i][0], acc[i][1], acc[i][2], acc[i][3]);
    }
}

// ---------------------------------------------------------------------------
extern "C" void kernel_launch(void* const* d_in, const int* in_sizes, int n_in,
                              void* d_out, int out_size, void* d_ws, size_t ws_size,
                              hipStream_t stream)
{
    const float* q   = (const float*)d_in[0];
    const float* k   = (const float*)d_in[1];
    const float* v   = (const float*)d_in[2];
    const float* W_q = (const float*)d_in[3];
    const float* W_k = (const float*)d_in[4];
    const float* W_v = (const float*)d_in[5];
    const float* W_o = (const float*)d_in[6];

    // Workspace: Qw, Kw, Vw ([B,H,T,DK]) and ctx ([B*T, D_MODEL]) — 16 MB each, 64 MB total
    float* ws  = (float*)d_ws;
    const size_t SEG = (size_t)BB * NHEADS * TT * DK;  // 4,194,304 floats
    float* Qw  = ws;
    float* Kw  = ws + SEG;
    float* Vw  = ws + 2 * SEG;
    float* ctx = ws + 3 * SEG;

    dim3 g1(D_MODEL / 64, MM / 64, 3);   // (16, 64, 3)
    qkv_rope_kernel<<<g1, 256, 0, stream>>>(q, k, v, W_q, W_k, W_v, Qw, Kw, Vw);

    dim3 g2(TT / 64, BB * NHEADS);       // (32, 32)
    attn_kernel<<<g2, 256, 0, stream>>>(Qw, Kw, Vw, ctx);

    dim3 g3(D_MODEL / 64, MM / 64);      // (16, 64)
    out_proj_kernel<<<g3, 256, 0, stream>>>(ctx, W_o, (float*)d_out);
}

// Round 3
// 628.372 us; speedup vs baseline: 1.7962x; 1.7962x over previous
//
#include <hip/hip_runtime.h>
#include <math.h>

// Problem constants (B=2, T=2048, D_MODEL=1024, H=16, D_K=64)
#define D_MODEL 1024
#define NHEADS  16
#define DK      64
#define TT      2048
#define BB      2
#define MM      (BB * TT)   // 4096 rows

typedef __attribute__((ext_vector_type(8))) short bf16x8;
typedef __attribute__((ext_vector_type(4))) float f32x4;
typedef __attribute__((ext_vector_type(4))) uint  u32x4;

__device__ __forceinline__ ushort f2bf(float f) {
    union { float f; uint u; } v; v.f = f;
    return (ushort)((v.u + 0x7FFFu + ((v.u >> 16) & 1u)) >> 16);   // RNE
}
__device__ __forceinline__ uint packbf(float lo, float hi) {
    return (uint)f2bf(lo) | ((uint)f2bf(hi) << 16);
}

// ---------------------------------------------------------------------------
// Kernel 1: fused QKV projection (fp32 GEMM) + RoPE epilogue, bf16 outputs.
//   z=0: Q (rope) -> [bh][t][64] bf16
//   z=1: K (rope) -> [bh][t][64] bf16
//   z=2: V        -> [bh][64][t] bf16 (TRANSPOSED for PV MFMA B-fragments)
// ---------------------------------------------------------------------------
__global__ __launch_bounds__(256) void qkv_rope_kernel(
    const float* __restrict__ qin, const float* __restrict__ kin, const float* __restrict__ vin,
    const float* __restrict__ Wq,  const float* __restrict__ Wk,  const float* __restrict__ Wv,
    ushort* __restrict__ Qb, ushort* __restrict__ Kb, ushort* __restrict__ Vb)
{
    const int z = blockIdx.z;
    const float* __restrict__ A = (z == 0) ? qin : (z == 1) ? kin : vin;
    const float* __restrict__ W = (z == 0) ? Wq  : (z == 1) ? Wk  : Wv;

    __shared__ float As[16][64 + 4];   // [k][m]
    __shared__ float Bs[16][64 + 4];   // [k][n]

    const int tid = threadIdx.x;
    const int tx = tid & 15, ty = tid >> 4;
    const int row0 = blockIdx.y << 6;
    const int col0 = blockIdx.x << 6;   // head h = blockIdx.x
    const int lr = tid >> 2;
    const int lc = (tid & 3) << 2;

    float acc[4][4] = {};

    for (int k0 = 0; k0 < D_MODEL; k0 += 16) {
        float4 av = *(const float4*)&A[(size_t)(row0 + lr) * D_MODEL + k0 + lc];
        float4 bv = *(const float4*)&W[(size_t)(col0 + lr) * D_MODEL + k0 + lc];
        As[lc + 0][lr] = av.x; As[lc + 1][lr] = av.y; As[lc + 2][lr] = av.z; As[lc + 3][lr] = av.w;
        Bs[lc + 0][lr] = bv.x; Bs[lc + 1][lr] = bv.y; Bs[lc + 2][lr] = bv.z; Bs[lc + 3][lr] = bv.w;
        __syncthreads();
#pragma unroll
        for (int kk = 0; kk < 16; ++kk) {
            float4 a = *(const float4*)&As[kk][ty << 2];
            float4 b = *(const float4*)&Bs[kk][tx << 2];
            const float aa[4] = {a.x, a.y, a.z, a.w};
            const float bb[4] = {b.x, b.y, b.z, b.w};
#pragma unroll
            for (int i = 0; i < 4; ++i)
#pragma unroll
                for (int j = 0; j < 4; ++j)
                    acc[i][j] = fmaf(aa[i], bb[j], acc[i][j]);
        }
        __syncthreads();
    }

    const int h  = blockIdx.x;
    const int d0 = tx << 2;
    const int t0 = (row0 & (TT - 1)) + (ty << 2);
    const int bidx = row0 >> 11;                 // batch (row0 multiple of 64)
    const size_t bh = (size_t)bidx * NHEADS + h;

    if (z < 2) {
        // RoPE + row-major bf16 write
        const float lb_over_dk = 9.210340371976184f / 64.0f;  // ln(10000)/64
        const float inv0 = __expf(-(float)(d0)     * lb_over_dk);
        const float inv1 = __expf(-(float)(d0 + 2) * lb_over_dk);
        ushort* dst = (z == 0) ? Qb : Kb;
#pragma unroll
        for (int i = 0; i < 4; ++i) {
            const int t = t0 + i;
            float c0, s0, c1, s1;
            __sincosf((float)t * inv0, &s0, &c0);
            __sincosf((float)t * inv1, &s1, &c1);
            ushort4 o;
            o.x = f2bf(acc[i][0] * c0 - acc[i][1] * s0);
            o.y = f2bf(acc[i][0] * s0 + acc[i][1] * c0);
            o.z = f2bf(acc[i][2] * c1 - acc[i][3] * s1);
            o.w = f2bf(acc[i][2] * s1 + acc[i][3] * c1);
            *(ushort4*)&dst[(bh * TT + t) * DK + d0] = o;
        }
    } else {
        // V transposed: Vb[bh][d][t]
#pragma unroll
        for (int j = 0; j < 4; ++j) {
            ushort4 o;
            o.x = f2bf(acc[0][j]); o.y = f2bf(acc[1][j]);
            o.z = f2bf(acc[2][j]); o.w = f2bf(acc[3][j]);
            *(ushort4*)&Vb[(bh * DK + d0 + j) * TT + t0] = o;
        }
    }
}

// ---------------------------------------------------------------------------
// Kernel 2: bf16 MFMA flash attention.
// Block = 256 threads = 4 waves; wave w owns 16 q-rows; KVBLK = 64.
// Swapped QK^T (mfma(K,Q) -> S^T: lane holds keys {16c+4g+r} of q=lane&15).
// P kept in registers, redistributed to PV B-fragments via shfl.
// K and V^T tiles staged in LDS with XOR swizzle (byte ^= (row&7)<<4).
// ---------------------------------------------------------------------------
__global__ __launch_bounds__(256) void attn_kernel(
    const ushort* __restrict__ Qw, const ushort* __restrict__ Kw,
    const ushort* __restrict__ Vtw, float* __restrict__ ctx)
{
    __shared__ ushort Ks[64 * 64];   // swizzled [key][dk]
    __shared__ ushort Vs[64 * 64];   // swizzled [d][key]

    const int tid  = threadIdx.x;
    const int lane = tid & 63;
    const int w    = tid >> 6;       // wave 0..3
    const int qi   = lane & 15;      // q within wave tile
    const int g    = lane >> 4;      // 0..3
    const int bh   = blockIdx.y;     // 0..31
    const int q0   = blockIdx.x << 6;

    const ushort* Qp = Qw  + (size_t)bh * TT * DK;
    const ushort* Kp = Kw  + (size_t)bh * TT * DK;
    const ushort* Vp = Vtw + (size_t)bh * DK * TT;

    // Q fragments (B-operand), K-step s: Q[q][32s + 8g + j], once per block
    const int qrow = q0 + w * 16 + qi;
    bf16x8 qf0 = *(const bf16x8*)&Qp[(size_t)qrow * DK + 8 * g];
    bf16x8 qf1 = *(const bf16x8*)&Qp[(size_t)qrow * DK + 32 + 8 * g];

    float m_i = -INFINITY, l_i = 0.0f;
    f32x4 o[4] = {};   // o[dt][r] = O^T[16dt+4g+r][q]

    // Staging addresses (thread handles chunks tid and tid+256 of 512)
    const int c0row = tid >> 3, c0col = tid & 7;
    const int c1row = (tid + 256) >> 3, c1col = tid & 7;  // (tid+256)&7 == tid&7
    const int sw0 = (c0col ^ (c0row & 7)) << 3;
    const int sw1 = (c1col ^ (c1row & 7)) << 3;

    for (int kt = 0; kt < TT; kt += 64) {
        // ---- stage K tile [64][64] and V^T tile [64][64], swizzled ----
        *(float4*)&Ks[c0row * 64 + sw0] = *(const float4*)&Kp[(size_t)(kt + c0row) * DK + c0col * 8];
        *(float4*)&Ks[c1row * 64 + sw1] = *(const float4*)&Kp[(size_t)(kt + c1row) * DK + c1col * 8];
        *(float4*)&Vs[c0row * 64 + sw0] = *(const float4*)&Vp[(size_t)c0row * TT + kt + c0col * 8];
        *(float4*)&Vs[c1row * 64 + sw1] = *(const float4*)&Vp[(size_t)c1row * TT + kt + c1col * 8];
        __syncthreads();

        // ---- S^T = K . Q^T (scaled): sv[c][r] = S[16c+4g+r][q] / 8 ----
        float sv[4][4];
#pragma unroll
        for (int c = 0; c < 4; ++c) {
            f32x4 acc = {};
            const int row = c * 16 + qi;
#pragma unroll
            for (int s = 0; s < 2; ++s) {
                const int col16 = (4 * s + g) ^ (row & 7);
                bf16x8 kf = *(const bf16x8*)&Ks[row * 64 + col16 * 8];
                acc = __builtin_amdgcn_mfma_f32_16x16x32_bf16(kf, (s == 0) ? qf0 : qf1, acc, 0, 0, 0);
            }
#pragma unroll
            for (int r = 0; r < 4; ++r) sv[c][r] = acc[r] * 0.125f;
        }

        // ---- online softmax (keys of q=lane&15 live in this lane + lanes ^16,^32) ----
        float mt = fmaxf(fmaxf(fmaxf(sv[0][0], sv[0][1]), fmaxf(sv[0][2], sv[0][3])),
                         fmaxf(fmaxf(sv[1][0], sv[1][1]), fmaxf(sv[1][2], sv[1][3])));
        mt = fmaxf(mt, fmaxf(fmaxf(fmaxf(sv[2][0], sv[2][1]), fmaxf(sv[2][2], sv[2][3])),
                             fmaxf(fmaxf(sv[3][0], sv[3][1]), fmaxf(sv[3][2], sv[3][3]))));
        mt = fmaxf(mt, __shfl_xor(mt, 16));
        mt = fmaxf(mt, __shfl_xor(mt, 32));
        const float mnew  = fmaxf(m_i, mt);
        const float alpha = __expf(m_i - mnew);
        m_i = mnew;

        float rs = 0.0f;
        uint pp[4][2];   // pp[c][rp] = bf16x2(keys 16c+4g+2rp, +1) of q
#pragma unroll
        for (int c = 0; c < 4; ++c) {
            float p0 = __expf(sv[c][0] - mnew);
            float p1 = __expf(sv[c][1] - mnew);
            float p2 = __expf(sv[c][2] - mnew);
            float p3 = __expf(sv[c][3] - mnew);
            rs += (p0 + p1) + (p2 + p3);
            pp[c][0] = packbf(p0, p1);
            pp[c][1] = packbf(p2, p3);
        }
        rs += __shfl_xor(rs, 16);
        rs += __shfl_xor(rs, 32);
        l_i = l_i * alpha + rs;
#pragma unroll
        for (int dt = 0; dt < 4; ++dt)
#pragma unroll
            for (int r = 0; r < 4; ++r) o[dt][r] *= alpha;

        // ---- redistribute P to PV B-fragment layout, accumulate O^T += V^T . P ----
#pragma unroll
        for (int s = 0; s < 2; ++s) {
            uint bu[4];
#pragma unroll
            for (int v = 0; v < 4; ++v) {
                const int srcl = ((2 * (g & 1) + (v >> 1)) << 4) + qi;
                const uint a = __shfl(pp[2 * s][v & 1], srcl);
                const uint b = __shfl(pp[2 * s + 1][v & 1], srcl);
                bu[v] = (g >> 1) ? b : a;
            }
            u32x4 bu4 = {bu[0], bu[1], bu[2], bu[3]};
            bf16x8 pf = __builtin_bit_cast(bf16x8, bu4);
#pragma unroll
            for (int dt = 0; dt < 4; ++dt) {
                const int row = dt * 16 + qi;
                const int col16 = (4 * s + g) ^ (row & 7);
                bf16x8 vf = *(const bf16x8*)&Vs[row * 64 + col16 * 8];
                o[dt] = __builtin_amdgcn_mfma_f32_16x16x32_bf16(vf, pf, o[dt], 0, 0, 0);
            }
        }
        __syncthreads();   // all LDS reads done before next-tile staging
    }

    // ---- epilogue: ctx[b*T + q][h*64 + d], fp32 ----
    const float inv = 1.0f / l_i;
    const int b = bh >> 4, h = bh & 15;
    float* dst = ctx + ((size_t)b * TT + qrow) * D_MODEL + h * DK;
#pragma unroll
    for (int dt = 0; dt < 4; ++dt) {
        float4 ov = make_float4(o[dt][0] * inv, o[dt][1] * inv, o[dt][2] * inv, o[dt][3] * inv);
        *(float4*)&dst[dt * 16 + 4 * g] = ov;
    }
}

// ---------------------------------------------------------------------------
// Kernel 3: output projection (fp32). out[m][o] = sum_c ctx[m][c] * W_o[o][c]
// ---------------------------------------------------------------------------
__global__ __launch_bounds__(256) void out_proj_kernel(
    const float* __restrict__ A, const float* __restrict__ W, float* __restrict__ C)
{
    __shared__ float As[16][64 + 4];
    __shared__ float Bs[16][64 + 4];

    const int tid = threadIdx.x;
    const int tx = tid & 15, ty = tid >> 4;
    const int row0 = blockIdx.y << 6;
    const int col0 = blockIdx.x << 6;
    const int lr = tid >> 2;
    const int lc = (tid & 3) << 2;

    float acc[4][4] = {};

    for (int k0 = 0; k0 < D_MODEL; k0 += 16) {
        float4 av = *(const float4*)&A[(size_t)(row0 + lr) * D_MODEL + k0 + lc];
        float4 bv = *(const float4*)&W[(size_t)(col0 + lr) * D_MODEL + k0 + lc];
        As[lc + 0][lr] = av.x; As[lc + 1][lr] = av.y; As[lc + 2][lr] = av.z; As[lc + 3][lr] = av.w;
        Bs[lc + 0][lr] = bv.x; Bs[lc + 1][lr] = bv.y; Bs[lc + 2][lr] = bv.z; Bs[lc + 3][lr] = bv.w;
        __syncthreads();
#pragma unroll
        for (int kk = 0; kk < 16; ++kk) {
            float4 a = *(const float4*)&As[kk][ty << 2];
            float4 b = *(const float4*)&Bs[kk][tx << 2];
            const float aa[4] = {a.x, a.y, a.z, a.w};
            const float bb[4] = {b.x, b.y, b.z, b.w};
#pragma unroll
            for (int i = 0; i < 4; ++i)
#pragma unroll
                for (int j = 0; j < 4; ++j)
                    acc[i][j] = fmaf(aa[i], bb[j], acc[i][j]);
        }
        __syncthreads();
    }

#pragma unroll
    for (int i = 0; i < 4; ++i) {
        const int m = row0 + (ty << 2) + i;
        *(float4*)&C[(size_t)m * D_MODEL + col0 + (tx << 2)] =
            make_float4(acc[i][0], acc[i][1], acc[i][2], acc[i][3]);
    }
}

// ---------------------------------------------------------------------------
extern "C" void kernel_launch(void* const* d_in, const int* in_sizes, int n_in,
                              void* d_out, int out_size, void* d_ws, size_t ws_size,
                              hipStream_t stream)
{
    const float* q   = (const float*)d_in[0];
    const float* k   = (const float*)d_in[1];
    const float* v   = (const float*)d_in[2];
    const float* W_q = (const float*)d_in[3];
    const float* W_k = (const float*)d_in[4];
    const float* W_v = (const float*)d_in[5];
    const float* W_o = (const float*)d_in[6];

    // ws: Qb, Kb (bf16 [bh][t][64]), Vb (bf16 [bh][64][t]) = 8MB each; ctx fp32 16MB
    ushort* ws = (ushort*)d_ws;
    const size_t SEG = (size_t)BB * NHEADS * TT * DK;   // 4,194,304 elements
    ushort* Qb = ws;
    ushort* Kb = ws + SEG;
    ushort* Vb = ws + 2 * SEG;
    float* ctx = (float*)(ws + 3 * SEG);

    dim3 g1(D_MODEL / 64, MM / 64, 3);
    qkv_rope_kernel<<<g1, 256, 0, stream>>>(q, k, v, W_q, W_k, W_v, Qb, Kb, Vb);

    dim3 g2(TT / 64, BB * NHEADS);
    attn_kernel<<<g2, 256, 0, stream>>>(Qb, Kb, Vb, ctx);

    dim3 g3(D_MODEL / 64, MM / 64);
    out_proj_kernel<<<g3, 256, 0, stream>>>(ctx, W_o, (float*)d_out);
}

// Round 6
// 355.302 us; speedup vs baseline: 3.1767x; 1.7686x over previous
//
#include <hip/hip_runtime.h>
#include <math.h>

// Problem constants (B=2, T=2048, D_MODEL=1024, H=16, D_K=64)
#define D_MODEL 1024
#define NHEADS  16
#define DK      64
#define TT      2048
#define BB      2
#define MM      (BB * TT)            // 4096 rows
#define SEG     ((size_t)4194304)    // 4096*1024 elements
#define WSEG    ((size_t)1048576)    // 1024*1024 elements

typedef __attribute__((ext_vector_type(8))) short bf16x8;
typedef __attribute__((ext_vector_type(4))) float f32x4;
typedef __attribute__((ext_vector_type(4))) uint  u32x4;

__device__ __forceinline__ ushort f2bf(float f) {
    union { float f; uint u; } v; v.f = f;
    return (ushort)((v.u + 0x7FFFu + ((v.u >> 16) & 1u)) >> 16);   // RNE
}
__device__ __forceinline__ float bf2f(ushort h) {
    union { uint u; float f; } v; v.u = (uint)h << 16;
    return v.f;
}
__device__ __forceinline__ uint packbf(float lo, float hi) {
    return (uint)f2bf(lo) | ((uint)f2bf(hi) << 16);
}
__device__ __forceinline__ void gld16(ushort* lds, const ushort* g) {
    __builtin_amdgcn_global_load_lds(
        (const __attribute__((address_space(1))) void*)g,
        (__attribute__((address_space(3))) void*)lds, 16, 0, 0);
}
__device__ __forceinline__ void split2(float x, ushort& h, ushort& l) {
    h = f2bf(x);
    l = f2bf(x - bf2f(h));
}

// ---------------------------------------------------------------------------
// Kernel 0a: split-cast the 4 weight matrices fp32 -> (hi, lo) bf16.
// ---------------------------------------------------------------------------
__global__ __launch_bounds__(256) void cast_w_kernel(
    const float* __restrict__ wq, const float* __restrict__ wk,
    const float* __restrict__ wv, const float* __restrict__ wo,
    ushort* __restrict__ WH, ushort* __restrict__ WL)
{
    const int a = blockIdx.y;
    const float* src = (a == 0) ? wq : (a == 1) ? wk : (a == 2) ? wv : wo;
    ushort* hi = WH + (size_t)a * WSEG;
    ushort* lo = WL + (size_t)a * WSEG;
    const size_t i = ((size_t)blockIdx.x * 256 + threadIdx.x) * 8;
#pragma unroll
    for (int c = 0; c < 2; ++c) {
        float4 f = *(const float4*)&src[i + 4 * c];
        ushort4 uh, ul;
        split2(f.x, uh.x, ul.x); split2(f.y, uh.y, ul.y);
        split2(f.z, uh.z, ul.z); split2(f.w, uh.w, ul.w);
        *(ushort4*)&hi[i + 4 * c] = uh;
        *(ushort4*)&lo[i + 4 * c] = ul;
    }
}

// Kernel 0b: split-cast one activation array (SEG elements).
__global__ __launch_bounds__(256) void cast_a_kernel(
    const float* __restrict__ src, ushort* __restrict__ hi, ushort* __restrict__ lo)
{
    const size_t i = ((size_t)blockIdx.x * 256 + threadIdx.x) * 8;
#pragma unroll
    for (int c = 0; c < 2; ++c) {
        float4 f = *(const float4*)&src[i + 4 * c];
        ushort4 uh, ul;
        split2(f.x, uh.x, ul.x); split2(f.y, uh.y, ul.y);
        split2(f.z, uh.z, ul.z); split2(f.w, uh.w, ul.w);
        *(ushort4*)&hi[i + 4 * c] = uh;
        *(ushort4*)&lo[i + 4 * c] = ul;
    }
}

// ---------------------------------------------------------------------------
// Split-bf16 (3-product) MFMA GEMM: C[m][n] = sum_k A[m][k] * W[n][k].
// A = Ah+Al, W = Wh+Wl; C ≈ Ah·Wh + Ah·Wl + Al·Wh (fp32 accum) — ~fp32 quality.
// M=4096, N=K=1024. 128x128 tile, BK=64, 256 thr = 4 waves (wave = 64x64).
// global_load_lds(16B) into linear LDS, pre-swizzled source (slot ^= row&7),
// swizzled ds_read_b128 fragment reads. Structure validated in round 4.
// Accumulator convention: acc[X][Y] where X is ALWAYS the epilogue's outer
// block axis (MODE 0/2: W-block ni; MODE 1: A-block mi) — round-5 audit found
// a transposed-acc bug here for MODE 1, fixed by accumulating into acc[j][i].
// MODE 0: Q/K proj (C^T orient, RoPE epilogue -> bf16 [bh][t][64])
// MODE 1: V proj   (C orient  -> bf16 V^T [bh][d][t], contiguous t)
// MODE 2: out proj (C^T orient -> fp32 float4 store)
// ---------------------------------------------------------------------------
template<int MODE>
__global__ __launch_bounds__(256) void gemm_kernel(
    const ushort* __restrict__ Ah, const ushort* __restrict__ Al,
    const ushort* __restrict__ Wh, const ushort* __restrict__ Wl,
    ushort* __restrict__ dst_bf, float* __restrict__ dst_f32)
{
    __shared__ ushort AsH[128 * 64];
    __shared__ ushort AsL[128 * 64];
    __shared__ ushort BsH[128 * 64];
    __shared__ ushort BsL[128 * 64];

    const int tid = threadIdx.x, lane = tid & 63, w = tid >> 6;
    const int g = lane >> 4, l15 = lane & 15;
    const int m0 = blockIdx.y << 7, n0 = blockIdx.x << 7;
    const int mw = (w >> 1) << 6, nw = (w & 1) << 6;

    // Staging: wave w covers 16B-slots s = w*256 + i*64 + lane, i=0..3.
    // Linear LDS slot s receives global slot (s&7)^(row&7) of row s>>3.
    int sOff[4], sBase[4];
#pragma unroll
    for (int i = 0; i < 4; ++i) {
        const int s = w * 256 + i * 64 + lane;
        const int r = s >> 3;
        sOff[i]  = r * 1024 + (((s & 7) ^ (r & 7)) << 3);   // ushort offset in global (lda=1024)
        sBase[i] = (w * 256 + i * 64) << 3;                 // ushort offset of wave-uniform LDS base
    }

    // Fragment read slot offsets (involution: read slot want^(row&7)).
    const int p0 = (g ^ (l15 & 7)) << 3;         // k-slice 0
    const int p1 = ((4 + g) ^ (l15 & 7)) << 3;   // k-slice 1

    f32x4 acc[4][4] = {};

    for (int k0 = 0; k0 < 1024; k0 += 64) {
        const ushort* pA = (size_t)m0 * 1024 + k0 + Ah;
        const ushort* pa = (size_t)m0 * 1024 + k0 + Al;
        const ushort* pW = (size_t)n0 * 1024 + k0 + Wh;
        const ushort* pw = (size_t)n0 * 1024 + k0 + Wl;
#pragma unroll
        for (int i = 0; i < 4; ++i) {
            gld16(&AsH[sBase[i]], pA + sOff[i]);
            gld16(&AsL[sBase[i]], pa + sOff[i]);
            gld16(&BsH[sBase[i]], pW + sOff[i]);
            gld16(&BsL[sBase[i]], pw + sOff[i]);
        }
        __syncthreads();

#pragma unroll
        for (int ks = 0; ks < 2; ++ks) {
            const int pk = ks ? p1 : p0;
            bf16x8 ah[4], al[4];
#pragma unroll
            for (int j = 0; j < 4; ++j) {
                ah[j] = *(const bf16x8*)&AsH[(mw + 16 * j + l15) * 64 + pk];
                al[j] = *(const bf16x8*)&AsL[(mw + 16 * j + l15) * 64 + pk];
            }
#pragma unroll
            for (int i = 0; i < 4; ++i) {
                bf16x8 wh = *(const bf16x8*)&BsH[(nw + 16 * i + l15) * 64 + pk];
                bf16x8 wl = *(const bf16x8*)&BsL[(nw + 16 * i + l15) * 64 + pk];
#pragma unroll
                for (int j = 0; j < 4; ++j) {
                    if (MODE == 1) {
                        // acc[j][i]: first index = A-block (t), matches epilogue
                        acc[j][i] = __builtin_amdgcn_mfma_f32_16x16x32_bf16(ah[j], wh, acc[j][i], 0, 0, 0);
                        acc[j][i] = __builtin_amdgcn_mfma_f32_16x16x32_bf16(ah[j], wl, acc[j][i], 0, 0, 0);
                        acc[j][i] = __builtin_amdgcn_mfma_f32_16x16x32_bf16(al[j], wh, acc[j][i], 0, 0, 0);
                    } else {
                        // acc[i][j]: first index = W-block (n), matches epilogue
                        acc[i][j] = __builtin_amdgcn_mfma_f32_16x16x32_bf16(wh, ah[j], acc[i][j], 0, 0, 0);
                        acc[i][j] = __builtin_amdgcn_mfma_f32_16x16x32_bf16(wl, ah[j], acc[i][j], 0, 0, 0);
                        acc[i][j] = __builtin_amdgcn_mfma_f32_16x16x32_bf16(wh, al[j], acc[i][j], 0, 0, 0);
                    }
                }
            }
        }
        __syncthreads();
    }

    // ---- epilogues ----
    if (MODE == 0) {
        // C^T: lane holds n = n0+nw+16ni+4g+r, m = m0+mw+16mj+l15. RoPE pairs lane-local.
        const float lb_over_dk = 9.210340371976184f / 64.0f;   // ln(10000)/64
#pragma unroll
        for (int ni = 0; ni < 4; ++ni) {
            const int nG = n0 + nw + 16 * ni + 4 * g;
            const int h  = nG >> 6;
            const int d0 = nG & 63;
            const float inv0 = __expf(-(float)(d0)     * lb_over_dk);
            const float inv1 = __expf(-(float)(d0 + 2) * lb_over_dk);
#pragma unroll
            for (int mj = 0; mj < 4; ++mj) {
                const int tG = m0 + mw + 16 * mj + l15;
                const int t  = tG & (TT - 1);
                const int b  = tG >> 11;
                const f32x4 x = acc[ni][mj];
                float c0, s0, c1, s1;
                __sincosf((float)t * inv0, &s0, &c0);
                __sincosf((float)t * inv1, &s1, &c1);
                ushort4 o;
                o.x = f2bf(x[0] * c0 - x[1] * s0);
                o.y = f2bf(x[0] * s0 + x[1] * c0);
                o.z = f2bf(x[2] * c1 - x[3] * s1);
                o.w = f2bf(x[2] * s1 + x[3] * c1);
                *(ushort4*)&dst_bf[(((size_t)b * NHEADS + h) * TT + t) * DK + d0] = o;
            }
        }
    } else if (MODE == 1) {
        // C: lane holds t = m0+mw+16mi+4g+r, d_global = n0+nw+16nj+l15.
#pragma unroll
        for (int mi = 0; mi < 4; ++mi) {
            const int tG = m0 + mw + 16 * mi + 4 * g;
            const int t  = tG & (TT - 1);
            const int b  = tG >> 11;
#pragma unroll
            for (int nj = 0; nj < 4; ++nj) {
                const int nG = n0 + nw + 16 * nj + l15;
                const int h  = nG >> 6;
                const int d  = nG & 63;
                const f32x4 x = acc[mi][nj];
                ushort4 o = {f2bf(x[0]), f2bf(x[1]), f2bf(x[2]), f2bf(x[3])};
                *(ushort4*)&dst_bf[(((size_t)b * NHEADS + h) * DK + d) * TT + t] = o;
            }
        }
    } else {
        // C^T: fp32 float4 store to d_out.
#pragma unroll
        for (int ni = 0; ni < 4; ++ni) {
            const int nG = n0 + nw + 16 * ni + 4 * g;
#pragma unroll
            for (int mj = 0; mj < 4; ++mj) {
                const int m = m0 + mw + 16 * mj + l15;
                const f32x4 x = acc[ni][mj];
                *(float4*)&dst_f32[(size_t)m * D_MODEL + nG] = make_float4(x[0], x[1], x[2], x[3]);
            }
        }
    }
}

// ---------------------------------------------------------------------------
// Kernel 2: bf16 MFMA flash attention (validated round 3). Epilogue now emits
// split (hi,lo) bf16 ctx so the out-projection keeps fp32-level accuracy.
// ---------------------------------------------------------------------------
__global__ __launch_bounds__(256) void attn_kernel(
    const ushort* __restrict__ Qw, const ushort* __restrict__ Kw,
    const ushort* __restrict__ Vtw, ushort* __restrict__ ctxH, ushort* __restrict__ ctxL)
{
    __shared__ ushort Ks[64 * 64];   // swizzled [key][dk]
    __shared__ ushort Vs[64 * 64];   // swizzled [d][key]

    const int tid  = threadIdx.x;
    const int lane = tid & 63;
    const int w    = tid >> 6;
    const int qi   = lane & 15;
    const int g    = lane >> 4;
    const int bh   = blockIdx.y;
    const int q0   = blockIdx.x << 6;

    const ushort* Qp = Qw  + (size_t)bh * TT * DK;
    const ushort* Kp = Kw  + (size_t)bh * TT * DK;
    const ushort* Vp = Vtw + (size_t)bh * DK * TT;

    const int qrow = q0 + w * 16 + qi;
    bf16x8 qf0 = *(const bf16x8*)&Qp[(size_t)qrow * DK + 8 * g];
    bf16x8 qf1 = *(const bf16x8*)&Qp[(size_t)qrow * DK + 32 + 8 * g];

    float m_i = -INFINITY, l_i = 0.0f;
    f32x4 o[4] = {};

    const int c0row = tid >> 3, c0col = tid & 7;
    const int c1row = (tid + 256) >> 3, c1col = tid & 7;
    const int sw0 = (c0col ^ (c0row & 7)) << 3;
    const int sw1 = (c1col ^ (c1row & 7)) << 3;

    for (int kt = 0; kt < TT; kt += 64) {
        *(float4*)&Ks[c0row * 64 + sw0] = *(const float4*)&Kp[(size_t)(kt + c0row) * DK + c0col * 8];
        *(float4*)&Ks[c1row * 64 + sw1] = *(const float4*)&Kp[(size_t)(kt + c1row) * DK + c1col * 8];
        *(float4*)&Vs[c0row * 64 + sw0] = *(const float4*)&Vp[(size_t)c0row * TT + kt + c0col * 8];
        *(float4*)&Vs[c1row * 64 + sw1] = *(const float4*)&Vp[(size_t)c1row * TT + kt + c1col * 8];
        __syncthreads();

        float sv[4][4];
#pragma unroll
        for (int c = 0; c < 4; ++c) {
            f32x4 acc = {};
            const int row = c * 16 + qi;
#pragma unroll
            for (int s = 0; s < 2; ++s) {
                const int col16 = (4 * s + g) ^ (row & 7);
                bf16x8 kf = *(const bf16x8*)&Ks[row * 64 + col16 * 8];
                acc = __builtin_amdgcn_mfma_f32_16x16x32_bf16(kf, (s == 0) ? qf0 : qf1, acc, 0, 0, 0);
            }
#pragma unroll
            for (int r = 0; r < 4; ++r) sv[c][r] = acc[r] * 0.125f;
        }

        float mt = fmaxf(fmaxf(fmaxf(sv[0][0], sv[0][1]), fmaxf(sv[0][2], sv[0][3])),
                         fmaxf(fmaxf(sv[1][0], sv[1][1]), fmaxf(sv[1][2], sv[1][3])));
        mt = fmaxf(mt, fmaxf(fmaxf(fmaxf(sv[2][0], sv[2][1]), fmaxf(sv[2][2], sv[2][3])),
                             fmaxf(fmaxf(sv[3][0], sv[3][1]), fmaxf(sv[3][2], sv[3][3]))));
        mt = fmaxf(mt, __shfl_xor(mt, 16));
        mt = fmaxf(mt, __shfl_xor(mt, 32));
        const float mnew  = fmaxf(m_i, mt);
        const float alpha = __expf(m_i - mnew);
        m_i = mnew;

        float rs = 0.0f;
        uint pp[4][2];
#pragma unroll
        for (int c = 0; c < 4; ++c) {
            float p0 = __expf(sv[c][0] - mnew);
            float p1 = __expf(sv[c][1] - mnew);
            float p2 = __expf(sv[c][2] - mnew);
            float p3 = __expf(sv[c][3] - mnew);
            rs += (p0 + p1) + (p2 + p3);
            pp[c][0] = packbf(p0, p1);
            pp[c][1] = packbf(p2, p3);
        }
        rs += __shfl_xor(rs, 16);
        rs += __shfl_xor(rs, 32);
        l_i = l_i * alpha + rs;
#pragma unroll
        for (int dt = 0; dt < 4; ++dt)
#pragma unroll
            for (int r = 0; r < 4; ++r) o[dt][r] *= alpha;

#pragma unroll
        for (int s = 0; s < 2; ++s) {
            uint bu[4];
#pragma unroll
            for (int v = 0; v < 4; ++v) {
                const int srcl = ((2 * (g & 1) + (v >> 1)) << 4) + qi;
                const uint a = __shfl(pp[2 * s][v & 1], srcl);
                const uint b = __shfl(pp[2 * s + 1][v & 1], srcl);
                bu[v] = (g >> 1) ? b : a;
            }
            u32x4 bu4 = {bu[0], bu[1], bu[2], bu[3]};
            bf16x8 pf = __builtin_bit_cast(bf16x8, bu4);
#pragma unroll
            for (int dt = 0; dt < 4; ++dt) {
                const int row = dt * 16 + qi;
                const int col16 = (4 * s + g) ^ (row & 7);
                bf16x8 vf = *(const bf16x8*)&Vs[row * 64 + col16 * 8];
                o[dt] = __builtin_amdgcn_mfma_f32_16x16x32_bf16(vf, pf, o[dt], 0, 0, 0);
            }
        }
        __syncthreads();
    }

    // epilogue: split-bf16 ctx[b*T + q][h*64 + d]
    const float inv = 1.0f / l_i;
    const int b = bh >> 4, h = bh & 15;
    const size_t base = ((size_t)b * TT + qrow) * D_MODEL + h * DK;
#pragma unroll
    for (int dt = 0; dt < 4; ++dt) {
        ushort4 oh, ol;
#pragma unroll
        for (int r = 0; r < 4; ++r) {
            float val = o[dt][r] * inv;
            ushort hh, ll; split2(val, hh, ll);
            ((ushort*)&oh)[r] = hh;
            ((ushort*)&ol)[r] = ll;
        }
        *(ushort4*)&ctxH[base + dt * 16 + 4 * g] = oh;
        *(ushort4*)&ctxL[base + dt * 16 + 4 * g] = ol;
    }
}

// ---------------------------------------------------------------------------
extern "C" void kernel_launch(void* const* d_in, const int* in_sizes, int n_in,
                              void* d_out, int out_size, void* d_ws, size_t ws_size,
                              hipStream_t stream)
{
    const float* q   = (const float*)d_in[0];
    const float* k   = (const float*)d_in[1];
    const float* v   = (const float*)d_in[2];
    const float* W_q = (const float*)d_in[3];
    const float* W_k = (const float*)d_in[4];
    const float* W_v = (const float*)d_in[5];
    const float* W_o = (const float*)d_in[6];

    // ws (ushorts), peak 58.7 MB:
    //   actH[SEG] actL[SEG]            (reused q -> k -> v; then ctxH/ctxL)
    //   WH[4*WSEG] WL[4*WSEG]
    //   Qb[SEG] Kb[SEG] Vtb[SEG]
    ushort* ws   = (ushort*)d_ws;
    ushort* actH = ws;
    ushort* actL = actH + SEG;
    ushort* WH   = actL + SEG;
    ushort* WL   = WH + 4 * WSEG;
    ushort* Qb   = WL + 4 * WSEG;
    ushort* Kb   = Qb + SEG;
    ushort* Vtb  = Kb + SEG;
    ushort* ctxH = actH;   // reuse after V projection
    ushort* ctxL = actL;

    cast_w_kernel<<<dim3(512, 4), 256, 0, stream>>>(W_q, W_k, W_v, W_o, WH, WL);

    // Q projection (+RoPE)
    cast_a_kernel<<<2048, 256, 0, stream>>>(q, actH, actL);
    gemm_kernel<0><<<dim3(8, 32), 256, 0, stream>>>(actH, actL, WH, WL, Qb, nullptr);
    // K projection (+RoPE)
    cast_a_kernel<<<2048, 256, 0, stream>>>(k, actH, actL);
    gemm_kernel<0><<<dim3(8, 32), 256, 0, stream>>>(actH, actL, WH + WSEG, WL + WSEG, Kb, nullptr);
    // V projection -> V^T
    cast_a_kernel<<<2048, 256, 0, stream>>>(v, actH, actL);
    gemm_kernel<1><<<dim3(8, 32), 256, 0, stream>>>(actH, actL, WH + 2 * WSEG, WL + 2 * WSEG, Vtb, nullptr);

    attn_kernel<<<dim3(TT / 64, BB * NHEADS), 256, 0, stream>>>(Qb, Kb, Vtb, ctxH, ctxL);

    gemm_kernel<2><<<dim3(8, 32), 256, 0, stream>>>(ctxH, ctxL, WH + 3 * WSEG, WL + 3 * WSEG,
                                                    nullptr, (float*)d_out);
}

// Round 7
// 337.042 us; speedup vs baseline: 3.3488x; 1.0542x over previous
//
#include <hip/hip_runtime.h>
#include <math.h>

// Problem constants (B=2, T=2048, D_MODEL=1024, H=16, D_K=64)
#define D_MODEL 1024
#define NHEADS  16
#define DK      64
#define TT      2048
#define BB      2
#define MM      (BB * TT)            // 4096 rows
#define SEG     ((size_t)4194304)    // 4096*1024 elements
#define WSEG    ((size_t)1048576)    // 1024*1024 elements

typedef __attribute__((ext_vector_type(8))) short bf16x8;
typedef __attribute__((ext_vector_type(4))) float f32x4;
typedef __attribute__((ext_vector_type(4))) uint  u32x4;

__device__ __forceinline__ ushort f2bf(float f) {
    union { float f; uint u; } v; v.f = f;
    return (ushort)((v.u + 0x7FFFu + ((v.u >> 16) & 1u)) >> 16);   // RNE
}
__device__ __forceinline__ float bf2f(ushort h) {
    union { uint u; float f; } v; v.u = (uint)h << 16;
    return v.f;
}
__device__ __forceinline__ uint packbf(float lo, float hi) {
    return (uint)f2bf(lo) | ((uint)f2bf(hi) << 16);
}
__device__ __forceinline__ void gld16(ushort* lds, const ushort* g) {
    __builtin_amdgcn_global_load_lds(
        (const __attribute__((address_space(1))) void*)g,
        (__attribute__((address_space(3))) void*)lds, 16, 0, 0);
}
__device__ __forceinline__ void split2(float x, ushort& h, ushort& l) {
    h = f2bf(x);
    l = f2bf(x - bf2f(h));
}

// ---------------------------------------------------------------------------
// Kernel 0a: split-cast the 4 weight matrices fp32 -> (hi, lo) bf16.
// ---------------------------------------------------------------------------
__global__ __launch_bounds__(256) void cast_w_kernel(
    const float* __restrict__ wq, const float* __restrict__ wk,
    const float* __restrict__ wv, const float* __restrict__ wo,
    ushort* __restrict__ WH, ushort* __restrict__ WL)
{
    const int a = blockIdx.y;
    const float* src = (a == 0) ? wq : (a == 1) ? wk : (a == 2) ? wv : wo;
    ushort* hi = WH + (size_t)a * WSEG;
    ushort* lo = WL + (size_t)a * WSEG;
    const size_t i = ((size_t)blockIdx.x * 256 + threadIdx.x) * 8;
#pragma unroll
    for (int c = 0; c < 2; ++c) {
        float4 f = *(const float4*)&src[i + 4 * c];
        ushort4 uh, ul;
        split2(f.x, uh.x, ul.x); split2(f.y, uh.y, ul.y);
        split2(f.z, uh.z, ul.z); split2(f.w, uh.w, ul.w);
        *(ushort4*)&hi[i + 4 * c] = uh;
        *(ushort4*)&lo[i + 4 * c] = ul;
    }
}

// Kernel 0b: split-cast one activation array (SEG elements).
__global__ __launch_bounds__(256) void cast_a_kernel(
    const float* __restrict__ src, ushort* __restrict__ hi, ushort* __restrict__ lo)
{
    const size_t i = ((size_t)blockIdx.x * 256 + threadIdx.x) * 8;
#pragma unroll
    for (int c = 0; c < 2; ++c) {
        float4 f = *(const float4*)&src[i + 4 * c];
        ushort4 uh, ul;
        split2(f.x, uh.x, ul.x); split2(f.y, uh.y, ul.y);
        split2(f.z, uh.z, ul.z); split2(f.w, uh.w, ul.w);
        *(ushort4*)&hi[i + 4 * c] = uh;
        *(ushort4*)&lo[i + 4 * c] = ul;
    }
}

// ---------------------------------------------------------------------------
// Split-bf16 (3-product) MFMA GEMM, now 2-phase double-buffered (T3 minimal):
// C ≈ Ah·Wh + Ah·Wl + Al·Wh, fp32 accum. 128x128 tile, BK=64, 4 waves.
// LDS 128 KB: 2 buffers x 4 tiles x 16 KB. Stage(next) issued BEFORE
// compute(cur); single barrier per K-step drains vmcnt after ~500 cyc of MFMA.
// Static even/odd unroll (no runtime-indexed LDS buffer select).
// MODE 0: Q/K proj (z=blockIdx.z in {0,1}; C^T orient, RoPE -> bf16 [bh][t][64])
// MODE 1: V proj   (C orient -> bf16 V^T [bh][d][t]); acc[j][i] convention
// MODE 2: out proj (C^T orient -> fp32 float4 store)
// Epilogues byte-identical to validated round-6 kernel.
// ---------------------------------------------------------------------------
template<int MODE>
__global__ __launch_bounds__(256) void gemm_kernel(
    const ushort* __restrict__ Ah, const ushort* __restrict__ Al,
    const ushort* __restrict__ Wh, const ushort* __restrict__ Wl,
    ushort* __restrict__ dst_bf, float* __restrict__ dst_f32)
{
    if (MODE == 0) {
        const int z = blockIdx.z;
        Ah += (size_t)z * SEG;  Al += (size_t)z * SEG;
        Wh += (size_t)z * WSEG; Wl += (size_t)z * WSEG;
        dst_bf += (size_t)z * SEG;
    }

    __shared__ ushort AsH0[128 * 64]; __shared__ ushort AsH1[128 * 64];
    __shared__ ushort AsL0[128 * 64]; __shared__ ushort AsL1[128 * 64];
    __shared__ ushort BsH0[128 * 64]; __shared__ ushort BsH1[128 * 64];
    __shared__ ushort BsL0[128 * 64]; __shared__ ushort BsL1[128 * 64];

    const int tid = threadIdx.x, lane = tid & 63, w = tid >> 6;
    const int g = lane >> 4, l15 = lane & 15;
    const int m0 = blockIdx.y << 7, n0 = blockIdx.x << 7;
    const int mw = (w >> 1) << 6, nw = (w & 1) << 6;

    // Staging: wave w covers 16B-slots s = w*256 + i*64 + lane, i=0..3.
    // Linear LDS slot s receives global slot (s&7)^(row&7) of row s>>3.
    int sOff[4], sBase[4];
#pragma unroll
    for (int i = 0; i < 4; ++i) {
        const int s = w * 256 + i * 64 + lane;
        const int r = s >> 3;
        sOff[i]  = r * 1024 + (((s & 7) ^ (r & 7)) << 3);   // ushort offset in global (lda=1024)
        sBase[i] = (w * 256 + i * 64) << 3;                 // wave-uniform LDS ushort offset
    }

    // Fragment read slot offsets (involution: read slot want^(row&7)).
    const int p0 = (g ^ (l15 & 7)) << 3;         // k-slice 0
    const int p1 = ((4 + g) ^ (l15 & 7)) << 3;   // k-slice 1

    f32x4 acc[4][4] = {};

    auto stage = [&](ushort* dAH, ushort* dAL, ushort* dBH, ushort* dBL, int k0) {
        const ushort* pA = Ah + (size_t)m0 * 1024 + k0;
        const ushort* pa = Al + (size_t)m0 * 1024 + k0;
        const ushort* pW = Wh + (size_t)n0 * 1024 + k0;
        const ushort* pw = Wl + (size_t)n0 * 1024 + k0;
#pragma unroll
        for (int i = 0; i < 4; ++i) {
            gld16(dAH + sBase[i], pA + sOff[i]);
            gld16(dAL + sBase[i], pa + sOff[i]);
            gld16(dBH + sBase[i], pW + sOff[i]);
            gld16(dBL + sBase[i], pw + sOff[i]);
        }
    };

    auto compute = [&](const ushort* aH, const ushort* aL,
                       const ushort* bH, const ushort* bL) {
#pragma unroll
        for (int ks = 0; ks < 2; ++ks) {
            const int pk = ks ? p1 : p0;
            bf16x8 ah[4], al[4];
#pragma unroll
            for (int j = 0; j < 4; ++j) {
                ah[j] = *(const bf16x8*)&aH[(mw + 16 * j + l15) * 64 + pk];
                al[j] = *(const bf16x8*)&aL[(mw + 16 * j + l15) * 64 + pk];
            }
#pragma unroll
            for (int i = 0; i < 4; ++i) {
                bf16x8 wh = *(const bf16x8*)&bH[(nw + 16 * i + l15) * 64 + pk];
                bf16x8 wl = *(const bf16x8*)&bL[(nw + 16 * i + l15) * 64 + pk];
#pragma unroll
                for (int j = 0; j < 4; ++j) {
                    if (MODE == 1) {
                        // acc[j][i]: first index = A-block (t), matches epilogue
                        acc[j][i] = __builtin_amdgcn_mfma_f32_16x16x32_bf16(ah[j], wh, acc[j][i], 0, 0, 0);
                        acc[j][i] = __builtin_amdgcn_mfma_f32_16x16x32_bf16(ah[j], wl, acc[j][i], 0, 0, 0);
                        acc[j][i] = __builtin_amdgcn_mfma_f32_16x16x32_bf16(al[j], wh, acc[j][i], 0, 0, 0);
                    } else {
                        // acc[i][j]: first index = W-block (n), matches epilogue
                        acc[i][j] = __builtin_amdgcn_mfma_f32_16x16x32_bf16(wh, ah[j], acc[i][j], 0, 0, 0);
                        acc[i][j] = __builtin_amdgcn_mfma_f32_16x16x32_bf16(wl, ah[j], acc[i][j], 0, 0, 0);
                        acc[i][j] = __builtin_amdgcn_mfma_f32_16x16x32_bf16(wh, al[j], acc[i][j], 0, 0, 0);
                    }
                }
            }
        }
    };

    // prologue: stage tile 0 into buffer 0
    stage(AsH0, AsL0, BsH0, BsL0, 0);
    __syncthreads();

#pragma unroll
    for (int it = 0; it < 8; ++it) {
        const int k0 = it * 128;
        stage(AsH1, AsL1, BsH1, BsL1, k0 + 64);       // prefetch odd tile
        compute(AsH0, AsL0, BsH0, BsL0);              // compute even tile
        __syncthreads();                               // drains prefetch under compute
        if (it < 7) stage(AsH0, AsL0, BsH0, BsL0, k0 + 128);  // prefetch next even
        compute(AsH1, AsL1, BsH1, BsL1);              // compute odd tile
        __syncthreads();
    }

    // ---- epilogues (identical to validated round-6 kernel) ----
    if (MODE == 0) {
        // C^T: lane holds n = n0+nw+16ni+4g+r, m = m0+mw+16mj+l15. RoPE pairs lane-local.
        const float lb_over_dk = 9.210340371976184f / 64.0f;   // ln(10000)/64
#pragma unroll
        for (int ni = 0; ni < 4; ++ni) {
            const int nG = n0 + nw + 16 * ni + 4 * g;
            const int h  = nG >> 6;
            const int d0 = nG & 63;
            const float inv0 = __expf(-(float)(d0)     * lb_over_dk);
            const float inv1 = __expf(-(float)(d0 + 2) * lb_over_dk);
#pragma unroll
            for (int mj = 0; mj < 4; ++mj) {
                const int tG = m0 + mw + 16 * mj + l15;
                const int t  = tG & (TT - 1);
                const int b  = tG >> 11;
                const f32x4 x = acc[ni][mj];
                float c0, s0, c1, s1;
                __sincosf((float)t * inv0, &s0, &c0);
                __sincosf((float)t * inv1, &s1, &c1);
                ushort4 o;
                o.x = f2bf(x[0] * c0 - x[1] * s0);
                o.y = f2bf(x[0] * s0 + x[1] * c0);
                o.z = f2bf(x[2] * c1 - x[3] * s1);
                o.w = f2bf(x[2] * s1 + x[3] * c1);
                *(ushort4*)&dst_bf[(((size_t)b * NHEADS + h) * TT + t) * DK + d0] = o;
            }
        }
    } else if (MODE == 1) {
        // C: lane holds t = m0+mw+16mi+4g+r, d_global = n0+nw+16nj+l15.
#pragma unroll
        for (int mi = 0; mi < 4; ++mi) {
            const int tG = m0 + mw + 16 * mi + 4 * g;
            const int t  = tG & (TT - 1);
            const int b  = tG >> 11;
#pragma unroll
            for (int nj = 0; nj < 4; ++nj) {
                const int nG = n0 + nw + 16 * nj + l15;
                const int h  = nG >> 6;
                const int d  = nG & 63;
                const f32x4 x = acc[mi][nj];
                ushort4 o = {f2bf(x[0]), f2bf(x[1]), f2bf(x[2]), f2bf(x[3])};
                *(ushort4*)&dst_bf[(((size_t)b * NHEADS + h) * DK + d) * TT + t] = o;
            }
        }
    } else {
        // C^T: fp32 float4 store to d_out.
#pragma unroll
        for (int ni = 0; ni < 4; ++ni) {
            const int nG = n0 + nw + 16 * ni + 4 * g;
#pragma unroll
            for (int mj = 0; mj < 4; ++mj) {
                const int m = m0 + mw + 16 * mj + l15;
                const f32x4 x = acc[ni][mj];
                *(float4*)&dst_f32[(size_t)m * D_MODEL + nG] = make_float4(x[0], x[1], x[2], x[3]);
            }
        }
    }
}

// ---------------------------------------------------------------------------
// Kernel 2: bf16 MFMA flash attention (validated; unchanged from round 6).
// ---------------------------------------------------------------------------
__global__ __launch_bounds__(256) void attn_kernel(
    const ushort* __restrict__ Qw, const ushort* __restrict__ Kw,
    const ushort* __restrict__ Vtw, ushort* __restrict__ ctxH, ushort* __restrict__ ctxL)
{
    __shared__ ushort Ks[64 * 64];   // swizzled [key][dk]
    __shared__ ushort Vs[64 * 64];   // swizzled [d][key]

    const int tid  = threadIdx.x;
    const int lane = tid & 63;
    const int w    = tid >> 6;
    const int qi   = lane & 15;
    const int g    = lane >> 4;
    const int bh   = blockIdx.y;
    const int q0   = blockIdx.x << 6;

    const ushort* Qp = Qw  + (size_t)bh * TT * DK;
    const ushort* Kp = Kw  + (size_t)bh * TT * DK;
    const ushort* Vp = Vtw + (size_t)bh * DK * TT;

    const int qrow = q0 + w * 16 + qi;
    bf16x8 qf0 = *(const bf16x8*)&Qp[(size_t)qrow * DK + 8 * g];
    bf16x8 qf1 = *(const bf16x8*)&Qp[(size_t)qrow * DK + 32 + 8 * g];

    float m_i = -INFINITY, l_i = 0.0f;
    f32x4 o[4] = {};

    const int c0row = tid >> 3, c0col = tid & 7;
    const int c1row = (tid + 256) >> 3, c1col = tid & 7;
    const int sw0 = (c0col ^ (c0row & 7)) << 3;
    const int sw1 = (c1col ^ (c1row & 7)) << 3;

    for (int kt = 0; kt < TT; kt += 64) {
        *(float4*)&Ks[c0row * 64 + sw0] = *(const float4*)&Kp[(size_t)(kt + c0row) * DK + c0col * 8];
        *(float4*)&Ks[c1row * 64 + sw1] = *(const float4*)&Kp[(size_t)(kt + c1row) * DK + c1col * 8];
        *(float4*)&Vs[c0row * 64 + sw0] = *(const float4*)&Vp[(size_t)c0row * TT + kt + c0col * 8];
        *(float4*)&Vs[c1row * 64 + sw1] = *(const float4*)&Vp[(size_t)c1row * TT + kt + c1col * 8];
        __syncthreads();

        float sv[4][4];
#pragma unroll
        for (int c = 0; c < 4; ++c) {
            f32x4 acc = {};
            const int row = c * 16 + qi;
#pragma unroll
            for (int s = 0; s < 2; ++s) {
                const int col16 = (4 * s + g) ^ (row & 7);
                bf16x8 kf = *(const bf16x8*)&Ks[row * 64 + col16 * 8];
                acc = __builtin_amdgcn_mfma_f32_16x16x32_bf16(kf, (s == 0) ? qf0 : qf1, acc, 0, 0, 0);
            }
#pragma unroll
            for (int r = 0; r < 4; ++r) sv[c][r] = acc[r] * 0.125f;
        }

        float mt = fmaxf(fmaxf(fmaxf(sv[0][0], sv[0][1]), fmaxf(sv[0][2], sv[0][3])),
                         fmaxf(fmaxf(sv[1][0], sv[1][1]), fmaxf(sv[1][2], sv[1][3])));
        mt = fmaxf(mt, fmaxf(fmaxf(fmaxf(sv[2][0], sv[2][1]), fmaxf(sv[2][2], sv[2][3])),
                             fmaxf(fmaxf(sv[3][0], sv[3][1]), fmaxf(sv[3][2], sv[3][3]))));
        mt = fmaxf(mt, __shfl_xor(mt, 16));
        mt = fmaxf(mt, __shfl_xor(mt, 32));
        const float mnew  = fmaxf(m_i, mt);
        const float alpha = __expf(m_i - mnew);
        m_i = mnew;

        float rs = 0.0f;
        uint pp[4][2];
#pragma unroll
        for (int c = 0; c < 4; ++c) {
            float p0 = __expf(sv[c][0] - mnew);
            float p1 = __expf(sv[c][1] - mnew);
            float p2 = __expf(sv[c][2] - mnew);
            float p3 = __expf(sv[c][3] - mnew);
            rs += (p0 + p1) + (p2 + p3);
            pp[c][0] = packbf(p0, p1);
            pp[c][1] = packbf(p2, p3);
        }
        rs += __shfl_xor(rs, 16);
        rs += __shfl_xor(rs, 32);
        l_i = l_i * alpha + rs;
#pragma unroll
        for (int dt = 0; dt < 4; ++dt)
#pragma unroll
            for (int r = 0; r < 4; ++r) o[dt][r] *= alpha;

#pragma unroll
        for (int s = 0; s < 2; ++s) {
            uint bu[4];
#pragma unroll
            for (int v = 0; v < 4; ++v) {
                const int srcl = ((2 * (g & 1) + (v >> 1)) << 4) + qi;
                const uint a = __shfl(pp[2 * s][v & 1], srcl);
                const uint b = __shfl(pp[2 * s + 1][v & 1], srcl);
                bu[v] = (g >> 1) ? b : a;
            }
            u32x4 bu4 = {bu[0], bu[1], bu[2], bu[3]};
            bf16x8 pf = __builtin_bit_cast(bf16x8, bu4);
#pragma unroll
            for (int dt = 0; dt < 4; ++dt) {
                const int row = dt * 16 + qi;
                const int col16 = (4 * s + g) ^ (row & 7);
                bf16x8 vf = *(const bf16x8*)&Vs[row * 64 + col16 * 8];
                o[dt] = __builtin_amdgcn_mfma_f32_16x16x32_bf16(vf, pf, o[dt], 0, 0, 0);
            }
        }
        __syncthreads();
    }

    // epilogue: split-bf16 ctx[b*T + q][h*64 + d]
    const float inv = 1.0f / l_i;
    const int b = bh >> 4, h = bh & 15;
    const size_t base = ((size_t)b * TT + qrow) * D_MODEL + h * DK;
#pragma unroll
    for (int dt = 0; dt < 4; ++dt) {
        ushort4 oh, ol;
#pragma unroll
        for (int r = 0; r < 4; ++r) {
            float val = o[dt][r] * inv;
            ushort hh, ll; split2(val, hh, ll);
            ((ushort*)&oh)[r] = hh;
            ((ushort*)&ol)[r] = ll;
        }
        *(ushort4*)&ctxH[base + dt * 16 + 4 * g] = oh;
        *(ushort4*)&ctxL[base + dt * 16 + 4 * g] = ol;
    }
}

// ---------------------------------------------------------------------------
extern "C" void kernel_launch(void* const* d_in, const int* in_sizes, int n_in,
                              void* d_out, int out_size, void* d_ws, size_t ws_size,
                              hipStream_t stream)
{
    const float* q   = (const float*)d_in[0];
    const float* k   = (const float*)d_in[1];
    const float* v   = (const float*)d_in[2];
    const float* W_q = (const float*)d_in[3];
    const float* W_k = (const float*)d_in[4];
    const float* W_v = (const float*)d_in[5];
    const float* W_o = (const float*)d_in[6];

    // ws (ushorts), peak 75.5 MB (== round-3 proven footprint):
    //   AH[2*SEG] AL[2*SEG]   (q at 0, k at SEG; v reuses slot 0; ctx reuses slot 1)
    //   WH[4*WSEG] WL[4*WSEG]
    //   Qb[SEG] Kb[SEG] Vtb[SEG]  (contiguous; MODE0 z-offset relies on Kb = Qb+SEG)
    ushort* ws  = (ushort*)d_ws;
    ushort* AH  = ws;
    ushort* AL  = AH + 2 * SEG;
    ushort* WH  = AL + 2 * SEG;
    ushort* WL  = WH + 4 * WSEG;
    ushort* Qb  = WL + 4 * WSEG;
    ushort* Kb  = Qb + SEG;
    ushort* Vtb = Kb + SEG;
    ushort* ctxH = AH + SEG;   // k-activation slot, free after QK GEMM
    ushort* ctxL = AL + SEG;

    cast_w_kernel<<<dim3(512, 4), 256, 0, stream>>>(W_q, W_k, W_v, W_o, WH, WL);

    // Q and K projections (+RoPE), fused into one z=2 dispatch
    cast_a_kernel<<<2048, 256, 0, stream>>>(q, AH, AL);
    cast_a_kernel<<<2048, 256, 0, stream>>>(k, AH + SEG, AL + SEG);
    gemm_kernel<0><<<dim3(8, 32, 2), 256, 0, stream>>>(AH, AL, WH, WL, Qb, nullptr);

    // V projection -> V^T (reuses activation slot 0)
    cast_a_kernel<<<2048, 256, 0, stream>>>(v, AH, AL);
    gemm_kernel<1><<<dim3(8, 32), 256, 0, stream>>>(AH, AL, WH + 2 * WSEG, WL + 2 * WSEG, Vtb, nullptr);

    attn_kernel<<<dim3(TT / 64, BB * NHEADS), 256, 0, stream>>>(Qb, Kb, Vtb, ctxH, ctxL);

    gemm_kernel<2><<<dim3(8, 32), 256, 0, stream>>>(ctxH, ctxL, WH + 3 * WSEG, WL + 3 * WSEG,
                                                    nullptr, (float*)d_out);
}

// Round 10
// 320.006 us; speedup vs baseline: 3.5271x; 1.0532x over previous
//
#include <hip/hip_runtime.h>
#include <math.h>

// Problem constants (B=2, T=2048, D_MODEL=1024, H=16, D_K=64)
#define D_MODEL 1024
#define NHEADS  16
#define DK      64
#define TT      2048
#define BB      2
#define MM      (BB * TT)            // 4096 rows
#define SEG     ((size_t)4194304)    // 4096*1024 elements
#define WSEG    ((size_t)1048576)    // 1024*1024 elements

typedef __attribute__((ext_vector_type(8))) short bf16x8;
typedef __attribute__((ext_vector_type(4))) float f32x4;
typedef __attribute__((ext_vector_type(4))) uint  u32x4;

__device__ __forceinline__ ushort f2bf(float f) {
    union { float f; uint u; } v; v.f = f;
    return (ushort)((v.u + 0x7FFFu + ((v.u >> 16) & 1u)) >> 16);   // RNE
}
__device__ __forceinline__ float bf2f(ushort h) {
    union { uint u; float f; } v; v.u = (uint)h << 16;
    return v.f;
}
__device__ __forceinline__ uint packbf(float lo, float hi) {
    return (uint)f2bf(lo) | ((uint)f2bf(hi) << 16);
}
__device__ __forceinline__ void gld16(ushort* lds, const ushort* g) {
    __builtin_amdgcn_global_load_lds(
        (const __attribute__((address_space(1))) void*)g,
        (__attribute__((address_space(3))) void*)lds, 16, 0, 0);
}
__device__ __forceinline__ void split2(float x, ushort& h, ushort& l) {
    h = f2bf(x);
    l = f2bf(x - bf2f(h));
}

// ---------------------------------------------------------------------------
// Kernel 0a: split-cast the 4 weight matrices fp32 -> (hi, lo) bf16.
// ---------------------------------------------------------------------------
__global__ __launch_bounds__(256) void cast_w_kernel(
    const float* __restrict__ wq, const float* __restrict__ wk,
    const float* __restrict__ wv, const float* __restrict__ wo,
    ushort* __restrict__ WH, ushort* __restrict__ WL)
{
    const int a = blockIdx.y;
    const float* src = (a == 0) ? wq : (a == 1) ? wk : (a == 2) ? wv : wo;
    ushort* hi = WH + (size_t)a * WSEG;
    ushort* lo = WL + (size_t)a * WSEG;
    const size_t i = ((size_t)blockIdx.x * 256 + threadIdx.x) * 8;
#pragma unroll
    for (int c = 0; c < 2; ++c) {
        float4 f = *(const float4*)&src[i + 4 * c];
        ushort4 uh, ul;
        split2(f.x, uh.x, ul.x); split2(f.y, uh.y, ul.y);
        split2(f.z, uh.z, ul.z); split2(f.w, uh.w, ul.w);
        *(ushort4*)&hi[i + 4 * c] = uh;
        *(ushort4*)&lo[i + 4 * c] = ul;
    }
}

// Kernel 0b: split-cast one activation array (SEG elements).
__global__ __launch_bounds__(256) void cast_a_kernel(
    const float* __restrict__ src, ushort* __restrict__ hi, ushort* __restrict__ lo)
{
    const size_t i = ((size_t)blockIdx.x * 256 + threadIdx.x) * 8;
#pragma unroll
    for (int c = 0; c < 2; ++c) {
        float4 f = *(const float4*)&src[i + 4 * c];
        ushort4 uh, ul;
        split2(f.x, uh.x, ul.x); split2(f.y, uh.y, ul.y);
        split2(f.z, uh.z, ul.z); split2(f.w, uh.w, ul.w);
        *(ushort4*)&hi[i + 4 * c] = uh;
        *(ushort4*)&lo[i + 4 * c] = ul;
    }
}

// ---------------------------------------------------------------------------
// Split-bf16 (3-product) MFMA GEMM, 2-phase double-buffered (round-7 passing
// structure, UNCHANGED) + XCD-aware block swizzle (the ONLY new variable vs
// round 7): per-XCD block set covers 4 A-panels x 8 B-panels (6 MB, ~L2-fit)
// instead of re-fetching A panels on every XCD.
// MODE 0: Q/K proj (z in {0,1}; C^T orient, RoPE -> bf16 [bh][t][64])
// MODE 1: V proj   (C orient -> bf16 V^T [bh][d][t]); acc[j][i] convention
// MODE 2: out proj (C^T orient -> fp32 float4 store)
// ---------------------------------------------------------------------------
template<int MODE>
__global__ __launch_bounds__(256) void gemm_kernel(
    const ushort* __restrict__ Ah, const ushort* __restrict__ Al,
    const ushort* __restrict__ Wh, const ushort* __restrict__ Wl,
    ushort* __restrict__ dst_bf, float* __restrict__ dst_f32)
{
    if (MODE == 0) {
        const int z = blockIdx.z;
        Ah += (size_t)z * SEG;  Al += (size_t)z * SEG;
        Wh += (size_t)z * WSEG; Wl += (size_t)z * WSEG;
        dst_bf += (size_t)z * SEG;
    }

    __shared__ ushort AsH0[128 * 64]; __shared__ ushort AsH1[128 * 64];
    __shared__ ushort AsL0[128 * 64]; __shared__ ushort AsL1[128 * 64];
    __shared__ ushort BsH0[128 * 64]; __shared__ ushort BsH1[128 * 64];
    __shared__ ushort BsL0[128 * 64]; __shared__ ushort BsL1[128 * 64];

    const int tid = threadIdx.x, lane = tid & 63, w = tid >> 6;
    const int g = lane >> 4, l15 = lane & 15;

    // XCD swizzle (bijective on 8x32: bx = y&7, by = x + 8*(y>>3)).
    // Blocks with equal vid&7 share an XCD -> 4 A-panels x 8 B-panels per XCD.
    const int vid = blockIdx.x + (blockIdx.y << 3);
    const int bx  = (vid >> 3) & 7;
    const int by  = (vid & 7) + ((vid >> 6) << 3);
    const int m0 = by << 7, n0 = bx << 7;
    const int mw = (w >> 1) << 6, nw = (w & 1) << 6;

    // Staging: wave w covers 16B-slots s = w*256 + i*64 + lane, i=0..3.
    // Linear LDS slot s receives global slot (s&7)^(row&7) of row s>>3.
    int sOff[4], sBase[4];
#pragma unroll
    for (int i = 0; i < 4; ++i) {
        const int s = w * 256 + i * 64 + lane;
        const int r = s >> 3;
        sOff[i]  = r * 1024 + (((s & 7) ^ (r & 7)) << 3);   // ushort offset in global (lda=1024)
        sBase[i] = (w * 256 + i * 64) << 3;                 // wave-uniform LDS ushort offset
    }

    // Fragment read slot offsets (involution: read slot want^(row&7)).
    const int p0 = (g ^ (l15 & 7)) << 3;         // k-slice 0
    const int p1 = ((4 + g) ^ (l15 & 7)) << 3;   // k-slice 1

    f32x4 acc[4][4] = {};

    auto stage = [&](ushort* dAH, ushort* dAL, ushort* dBH, ushort* dBL, int k0) {
        const ushort* pA = Ah + (size_t)m0 * 1024 + k0;
        const ushort* pa = Al + (size_t)m0 * 1024 + k0;
        const ushort* pW = Wh + (size_t)n0 * 1024 + k0;
        const ushort* pw = Wl + (size_t)n0 * 1024 + k0;
#pragma unroll
        for (int i = 0; i < 4; ++i) {
            gld16(dAH + sBase[i], pA + sOff[i]);
            gld16(dAL + sBase[i], pa + sOff[i]);
            gld16(dBH + sBase[i], pW + sOff[i]);
            gld16(dBL + sBase[i], pw + sOff[i]);
        }
    };

    auto compute = [&](const ushort* aH, const ushort* aL,
                       const ushort* bH, const ushort* bL) {
#pragma unroll
        for (int ks = 0; ks < 2; ++ks) {
            const int pk = ks ? p1 : p0;
            bf16x8 ah[4], al[4];
#pragma unroll
            for (int j = 0; j < 4; ++j) {
                ah[j] = *(const bf16x8*)&aH[(mw + 16 * j + l15) * 64 + pk];
                al[j] = *(const bf16x8*)&aL[(mw + 16 * j + l15) * 64 + pk];
            }
#pragma unroll
            for (int i = 0; i < 4; ++i) {
                bf16x8 wh = *(const bf16x8*)&bH[(nw + 16 * i + l15) * 64 + pk];
                bf16x8 wl = *(const bf16x8*)&bL[(nw + 16 * i + l15) * 64 + pk];
#pragma unroll
                for (int j = 0; j < 4; ++j) {
                    if (MODE == 1) {
                        // acc[j][i]: first index = A-block (t), matches epilogue
                        acc[j][i] = __builtin_amdgcn_mfma_f32_16x16x32_bf16(ah[j], wh, acc[j][i], 0, 0, 0);
                        acc[j][i] = __builtin_amdgcn_mfma_f32_16x16x32_bf16(ah[j], wl, acc[j][i], 0, 0, 0);
                        acc[j][i] = __builtin_amdgcn_mfma_f32_16x16x32_bf16(al[j], wh, acc[j][i], 0, 0, 0);
                    } else {
                        // acc[i][j]: first index = W-block (n), matches epilogue
                        acc[i][j] = __builtin_amdgcn_mfma_f32_16x16x32_bf16(wh, ah[j], acc[i][j], 0, 0, 0);
                        acc[i][j] = __builtin_amdgcn_mfma_f32_16x16x32_bf16(wl, ah[j], acc[i][j], 0, 0, 0);
                        acc[i][j] = __builtin_amdgcn_mfma_f32_16x16x32_bf16(wh, al[j], acc[i][j], 0, 0, 0);
                    }
                }
            }
        }
    };

    // prologue: stage tile 0 into buffer 0 (round-7 passing flow, unchanged)
    stage(AsH0, AsL0, BsH0, BsL0, 0);
    __syncthreads();

#pragma unroll
    for (int it = 0; it < 8; ++it) {
        const int k0 = it * 128;
        stage(AsH1, AsL1, BsH1, BsL1, k0 + 64);       // prefetch odd tile
        compute(AsH0, AsL0, BsH0, BsL0);              // compute even tile
        __syncthreads();                               // drains prefetch under compute
        if (it < 7) stage(AsH0, AsL0, BsH0, BsL0, k0 + 128);  // prefetch next even
        compute(AsH1, AsL1, BsH1, BsL1);              // compute odd tile
        __syncthreads();
    }

    // ---- epilogues (identical to validated round-6/7 kernel) ----
    if (MODE == 0) {
        // C^T: lane holds n = n0+nw+16ni+4g+r, m = m0+mw+16mj+l15. RoPE pairs lane-local.
        const float lb_over_dk = 9.210340371976184f / 64.0f;   // ln(10000)/64
#pragma unroll
        for (int ni = 0; ni < 4; ++ni) {
            const int nG = n0 + nw + 16 * ni + 4 * g;
            const int h  = nG >> 6;
            const int d0 = nG & 63;
            const float inv0 = __expf(-(float)(d0)     * lb_over_dk);
            const float inv1 = __expf(-(float)(d0 + 2) * lb_over_dk);
#pragma unroll
            for (int mj = 0; mj < 4; ++mj) {
                const int tG = m0 + mw + 16 * mj + l15;
                const int t  = tG & (TT - 1);
                const int b  = tG >> 11;
                const f32x4 x = acc[ni][mj];
                float c0, s0, c1, s1;
                __sincosf((float)t * inv0, &s0, &c0);
                __sincosf((float)t * inv1, &s1, &c1);
                ushort4 o;
                o.x = f2bf(x[0] * c0 - x[1] * s0);
                o.y = f2bf(x[0] * s0 + x[1] * c0);
                o.z = f2bf(x[2] * c1 - x[3] * s1);
                o.w = f2bf(x[2] * s1 + x[3] * c1);
                *(ushort4*)&dst_bf[(((size_t)b * NHEADS + h) * TT + t) * DK + d0] = o;
            }
        }
    } else if (MODE == 1) {
        // C: lane holds t = m0+mw+16mi+4g+r, d_global = n0+nw+16nj+l15.
#pragma unroll
        for (int mi = 0; mi < 4; ++mi) {
            const int tG = m0 + mw + 16 * mi + 4 * g;
            const int t  = tG & (TT - 1);
            const int b  = tG >> 11;
#pragma unroll
            for (int nj = 0; nj < 4; ++nj) {
                const int nG = n0 + nw + 16 * nj + l15;
                const int h  = nG >> 6;
                const int d  = nG & 63;
                const f32x4 x = acc[mi][nj];
                ushort4 o = {f2bf(x[0]), f2bf(x[1]), f2bf(x[2]), f2bf(x[3])};
                *(ushort4*)&dst_bf[(((size_t)b * NHEADS + h) * DK + d) * TT + t] = o;
            }
        }
    } else {
        // C^T: fp32 float4 store to d_out.
#pragma unroll
        for (int ni = 0; ni < 4; ++ni) {
            const int nG = n0 + nw + 16 * ni + 4 * g;
#pragma unroll
            for (int mj = 0; mj < 4; ++mj) {
                const int m = m0 + mw + 16 * mj + l15;
                const f32x4 x = acc[ni][mj];
                *(float4*)&dst_f32[(size_t)m * D_MODEL + nG] = make_float4(x[0], x[1], x[2], x[3]);
            }
        }
    }
}

// ---------------------------------------------------------------------------
// Kernel 2: bf16 MFMA flash attention (validated; unchanged).
// ---------------------------------------------------------------------------
__global__ __launch_bounds__(256) void attn_kernel(
    const ushort* __restrict__ Qw, const ushort* __restrict__ Kw,
    const ushort* __restrict__ Vtw, ushort* __restrict__ ctxH, ushort* __restrict__ ctxL)
{
    __shared__ ushort Ks[64 * 64];   // swizzled [key][dk]
    __shared__ ushort Vs[64 * 64];   // swizzled [d][key]

    const int tid  = threadIdx.x;
    const int lane = tid & 63;
    const int w    = tid >> 6;
    const int qi   = lane & 15;
    const int g    = lane >> 4;
    const int bh   = blockIdx.y;
    const int q0   = blockIdx.x << 6;

    const ushort* Qp = Qw  + (size_t)bh * TT * DK;
    const ushort* Kp = Kw  + (size_t)bh * TT * DK;
    const ushort* Vp = Vtw + (size_t)bh * DK * TT;

    const int qrow = q0 + w * 16 + qi;
    bf16x8 qf0 = *(const bf16x8*)&Qp[(size_t)qrow * DK + 8 * g];
    bf16x8 qf1 = *(const bf16x8*)&Qp[(size_t)qrow * DK + 32 + 8 * g];

    float m_i = -INFINITY, l_i = 0.0f;
    f32x4 o[4] = {};

    const int c0row = tid >> 3, c0col = tid & 7;
    const int c1row = (tid + 256) >> 3, c1col = tid & 7;
    const int sw0 = (c0col ^ (c0row & 7)) << 3;
    const int sw1 = (c1col ^ (c1row & 7)) << 3;

    for (int kt = 0; kt < TT; kt += 64) {
        *(float4*)&Ks[c0row * 64 + sw0] = *(const float4*)&Kp[(size_t)(kt + c0row) * DK + c0col * 8];
        *(float4*)&Ks[c1row * 64 + sw1] = *(const float4*)&Kp[(size_t)(kt + c1row) * DK + c1col * 8];
        *(float4*)&Vs[c0row * 64 + sw0] = *(const float4*)&Vp[(size_t)c0row * TT + kt + c0col * 8];
        *(float4*)&Vs[c1row * 64 + sw1] = *(const float4*)&Vp[(size_t)c1row * TT + kt + c1col * 8];
        __syncthreads();

        float sv[4][4];
#pragma unroll
        for (int c = 0; c < 4; ++c) {
            f32x4 acc = {};
            const int row = c * 16 + qi;
#pragma unroll
            for (int s = 0; s < 2; ++s) {
                const int col16 = (4 * s + g) ^ (row & 7);
                bf16x8 kf = *(const bf16x8*)&Ks[row * 64 + col16 * 8];
                acc = __builtin_amdgcn_mfma_f32_16x16x32_bf16(kf, (s == 0) ? qf0 : qf1, acc, 0, 0, 0);
            }
#pragma unroll
            for (int r = 0; r < 4; ++r) sv[c][r] = acc[r] * 0.125f;
        }

        float mt = fmaxf(fmaxf(fmaxf(sv[0][0], sv[0][1]), fmaxf(sv[0][2], sv[0][3])),
                         fmaxf(fmaxf(sv[1][0], sv[1][1]), fmaxf(sv[1][2], sv[1][3])));
        mt = fmaxf(mt, fmaxf(fmaxf(fmaxf(sv[2][0], sv[2][1]), fmaxf(sv[2][2], sv[2][3])),
                             fmaxf(fmaxf(sv[3][0], sv[3][1]), fmaxf(sv[3][2], sv[3][3]))));
        mt = fmaxf(mt, __shfl_xor(mt, 16));
        mt = fmaxf(mt, __shfl_xor(mt, 32));
        const float mnew  = fmaxf(m_i, mt);
        const float alpha = __expf(m_i - mnew);
        m_i = mnew;

        float rs = 0.0f;
        uint pp[4][2];
#pragma unroll
        for (int c = 0; c < 4; ++c) {
            float p0 = __expf(sv[c][0] - mnew);
            float p1 = __expf(sv[c][1] - mnew);
            float p2 = __expf(sv[c][2] - mnew);
            float p3 = __expf(sv[c][3] - mnew);
            rs += (p0 + p1) + (p2 + p3);
            pp[c][0] = packbf(p0, p1);
            pp[c][1] = packbf(p2, p3);
        }
        rs += __shfl_xor(rs, 16);
        rs += __shfl_xor(rs, 32);
        l_i = l_i * alpha + rs;
#pragma unroll
        for (int dt = 0; dt < 4; ++dt)
#pragma unroll
            for (int r = 0; r < 4; ++r) o[dt][r] *= alpha;

#pragma unroll
        for (int s = 0; s < 2; ++s) {
            uint bu[4];
#pragma unroll
            for (int v = 0; v < 4; ++v) {
                const int srcl = ((2 * (g & 1) + (v >> 1)) << 4) + qi;
                const uint a = __shfl(pp[2 * s][v & 1], srcl);
                const uint b = __shfl(pp[2 * s + 1][v & 1], srcl);
                bu[v] = (g >> 1) ? b : a;
            }
            u32x4 bu4 = {bu[0], bu[1], bu[2], bu[3]};
            bf16x8 pf = __builtin_bit_cast(bf16x8, bu4);
#pragma unroll
            for (int dt = 0; dt < 4; ++dt) {
                const int row = dt * 16 + qi;
                const int col16 = (4 * s + g) ^ (row & 7);
                bf16x8 vf = *(const bf16x8*)&Vs[row * 64 + col16 * 8];
                o[dt] = __builtin_amdgcn_mfma_f32_16x16x32_bf16(vf, pf, o[dt], 0, 0, 0);
            }
        }
        __syncthreads();
    }

    // epilogue: split-bf16 ctx[b*T + q][h*64 + d]
    const float inv = 1.0f / l_i;
    const int b = bh >> 4, h = bh & 15;
    const size_t base = ((size_t)b * TT + qrow) * D_MODEL + h * DK;
#pragma unroll
    for (int dt = 0; dt < 4; ++dt) {
        ushort4 oh, ol;
#pragma unroll
        for (int r = 0; r < 4; ++r) {
            float val = o[dt][r] * inv;
            ushort hh, ll; split2(val, hh, ll);
            ((ushort*)&oh)[r] = hh;
            ((ushort*)&ol)[r] = ll;
        }
        *(ushort4*)&ctxH[base + dt * 16 + 4 * g] = oh;
        *(ushort4*)&ctxL[base + dt * 16 + 4 * g] = ol;
    }
}

// ---------------------------------------------------------------------------
extern "C" void kernel_launch(void* const* d_in, const int* in_sizes, int n_in,
                              void* d_out, int out_size, void* d_ws, size_t ws_size,
                              hipStream_t stream)
{
    const float* q   = (const float*)d_in[0];
    const float* k   = (const float*)d_in[1];
    const float* v   = (const float*)d_in[2];
    const float* W_q = (const float*)d_in[3];
    const float* W_k = (const float*)d_in[4];
    const float* W_v = (const float*)d_in[5];
    const float* W_o = (const float*)d_in[6];

    // ws (ushorts), peak 72 MB:
    //   AH[2*SEG] AL[2*SEG]   (q at 0, k at SEG; v reuses slot 0; ctx reuses slot 1)
    //   WH[4*WSEG] WL[4*WSEG]
    //   Qb[SEG] Kb[SEG] Vtb[SEG]  (contiguous; MODE0 z-offset relies on Kb = Qb+SEG)
    ushort* ws  = (ushort*)d_ws;
    ushort* AH  = ws;
    ushort* AL  = AH + 2 * SEG;
    ushort* WH  = AL + 2 * SEG;
    ushort* WL  = WH + 4 * WSEG;
    ushort* Qb  = WL + 4 * WSEG;
    ushort* Kb  = Qb + SEG;
    ushort* Vtb = Kb + SEG;
    ushort* ctxH = AH + SEG;   // k-activation slot, free after QK GEMM
    ushort* ctxL = AL + SEG;

    cast_w_kernel<<<dim3(512, 4), 256, 0, stream>>>(W_q, W_k, W_v, W_o, WH, WL);

    // Q and K projections (+RoPE), fused into one z=2 dispatch
    cast_a_kernel<<<2048, 256, 0, stream>>>(q, AH, AL);
    cast_a_kernel<<<2048, 256, 0, stream>>>(k, AH + SEG, AL + SEG);
    gemm_kernel<0><<<dim3(8, 32, 2), 256, 0, stream>>>(AH, AL, WH, WL, Qb, nullptr);

    // V projection -> V^T (reuses activation slot 0)
    cast_a_kernel<<<2048, 256, 0, stream>>>(v, AH, AL);
    gemm_kernel<1><<<dim3(8, 32), 256, 0, stream>>>(AH, AL, WH + 2 * WSEG, WL + 2 * WSEG, Vtb, nullptr);

    attn_kernel<<<dim3(TT / 64, BB * NHEADS), 256, 0, stream>>>(Qb, Kb, Vtb, ctxH, ctxL);

    gemm_kernel<2><<<dim3(8, 32), 256, 0, stream>>>(ctxH, ctxL, WH + 3 * WSEG, WL + 3 * WSEG,
                                                    nullptr, (float*)d_out);
}